// Round 21
// baseline (194.690 us; speedup 1.0000x reference)
//
#include <hip/hip_runtime.h>

// H2GCN: CSR build -> bf16 SpMM x2 (masked unroll-8) -> fused_gemm v7:
// stage B with ZERO barriers -- A tile seg-resident in LDS (32KB), W slices
// in per-wave PRIVATE double-buffers synced by per-wave vmcnt (wave w only
// reads its own j-quarter). WcT whole into freed A region; Tl aliases W
// region. 4 barriers/seg (was ~16).

#define FD 256    // D == H == 256
#define CO 64     // out channels
#define SB 512    // scan block

using frag_ab = __attribute__((ext_vector_type(8))) short;  // 8 bf16
using f32x4   = __attribute__((ext_vector_type(4))) float;
typedef unsigned short u16;
typedef unsigned int   u32;

__device__ __forceinline__ u16 f2bf(float f) {
    u32 u = __builtin_bit_cast(u32, f);
    return (u16)((u + 0x7FFFu + ((u >> 16) & 1u)) >> 16);
}
__device__ __forceinline__ float bfl(u32 packed) {          // low bf16
    return __builtin_bit_cast(float, packed << 16);
}
__device__ __forceinline__ float bfh(u32 packed) {          // high bf16
    return __builtin_bit_cast(float, packed & 0xFFFF0000u);
}

__device__ __forceinline__ void gll16(const void* g, void* l) {
    __builtin_amdgcn_global_load_lds(
        (const __attribute__((address_space(1))) u32*)g,
        (__attribute__((address_space(3))) u32*)l, 16, 0, 0);
}

#define BAR()  __builtin_amdgcn_s_barrier()
#define WLG0() asm volatile("s_waitcnt lgkmcnt(0)" ::: "memory")
#define WVM0() asm volatile("s_waitcnt vmcnt(0)" ::: "memory")
#define WVM4() asm volatile("s_waitcnt vmcnt(4)" ::: "memory")

// ---------------- CSR build ----------------
__global__ void zerok(int4* __restrict__ deg4, int4* __restrict__ fill4, int n4) {
    int i = blockIdx.x * blockDim.x + threadIdx.x;
    int4 z = make_int4(0, 0, 0, 0);
    if (i < n4) { deg4[i] = z; fill4[i] = z; }
}
__global__ void count_kernel(const int* __restrict__ ei0, int* deg, int e) {
    int i = blockIdx.x * blockDim.x + threadIdx.x;
    if (i < e) atomicAdd(&deg[ei0[i]], 1);
}
// deg holds RAW edge counts; +1 self-loop added here
__global__ void scan1(const int* __restrict__ deg, int* __restrict__ rowptr,
                      int* __restrict__ bsum, float* __restrict__ dis, int n) {
    __shared__ int sh[SB];
    int tid = threadIdx.x;
    int i = blockIdx.x * SB + tid;
    int v = (i < n) ? deg[i] + 1 : 0;
    if (i < n) dis[i] = rsqrtf((float)v);
    sh[tid] = v;
    __syncthreads();
    for (int off = 1; off < SB; off <<= 1) {
        int add = (tid >= off) ? sh[tid - off] : 0;
        __syncthreads();
        sh[tid] += add;
        __syncthreads();
    }
    if (i < n) rowptr[i] = sh[tid] - v;
    if (tid == SB - 1) bsum[blockIdx.x] = sh[tid];
}
__global__ void scan2(const int* __restrict__ bsum, int* __restrict__ bscan, int nb) {
    __shared__ int sh[128];
    int tid = threadIdx.x;
    int v = (tid < nb) ? bsum[tid] : 0;
    sh[tid] = v;
    __syncthreads();
    for (int off = 1; off < 128; off <<= 1) {
        int add = (tid >= off) ? sh[tid - off] : 0;
        __syncthreads();
        sh[tid] += add;
        __syncthreads();
    }
    if (tid < nb) bscan[tid] = sh[tid] - v;
    if (tid == nb - 1) bscan[nb] = sh[tid];
}
__global__ void scan3(int* rowptr, const int* __restrict__ bscan, int n, int nb) {
    int i = blockIdx.x * 256 + threadIdx.x;
    if (i < n) rowptr[i] += bscan[i / SB];
    if (i == n) rowptr[n] = bscan[nb];
}
__global__ void fill_kernel(const int* __restrict__ ei, const float* __restrict__ dis,
                            const int* __restrict__ rowptr, int* fill,
                            int2* __restrict__ cw, int e, int n) {
    int i = blockIdx.x * blockDim.x + threadIdx.x;
    if (i >= e + n) return;
    int r, c;
    if (i < e) { r = ei[i]; c = ei[e + i]; }
    else       { r = i - e; c = r; }
    float w = dis[r] * dis[c];
    int pos = rowptr[r] + atomicAdd(&fill[r], 1);
    int2 p; p.x = c; p.y = __float_as_int(w);
    cw[pos] = p;
}

// ---------------- prep: x->bf16 convert (blocks < cb) + weight transpose ----------------
__global__ void prep_kernel(const float* __restrict__ x, u16* __restrict__ xb, int total4, int cb,
                            const float* __restrict__ W0, const float* __restrict__ W1,
                            const float* __restrict__ W2, const float* __restrict__ Wc,
                            u16* __restrict__ WkT, u16* __restrict__ WcT) {
    __shared__ u16 tl[64][65];
    if (blockIdx.x < cb) {
        int i = blockIdx.x * blockDim.x + threadIdx.x;
        if (i < total4) {
            float4 v = ((const float4*)x)[i];
            ushort4 o;
            o.x = f2bf(v.x); o.y = f2bf(v.y); o.z = f2bf(v.z); o.w = f2bf(v.w);
            ((ushort4*)xb)[i] = o;
        }
        return;
    }
    int b = blockIdx.x - cb;           // 0..59
    const float* src; u16* dst; int R, C, r0, c0;
    if (b < 48) {
        int k = b >> 4, t = b & 15;
        src = (k == 0) ? W0 : (k == 1) ? W1 : W2;
        dst = WkT + k * 65536;
        R = 256; C = 256; r0 = (t >> 2) * 64; c0 = (t & 3) * 64;
    } else {
        int t = b - 48;
        src = Wc; dst = WcT;
        R = 768; C = 64; r0 = t * 64; c0 = 0;
    }
    int tid = threadIdx.x;
    int rr = tid >> 4, cc = (tid & 15) * 4;
    #pragma unroll
    for (int it = 0; it < 4; ++it) {
        int r = it * 16 + rr;
        float4 v = *(const float4*)(src + (size_t)(r0 + r) * C + c0 + cc);
        tl[cc + 0][r] = f2bf(v.x); tl[cc + 1][r] = f2bf(v.y);
        tl[cc + 2][r] = f2bf(v.z); tl[cc + 3][r] = f2bf(v.w);
    }
    __syncthreads();
    #pragma unroll
    for (int it = 0; it < 4; ++it) {
        int crow = it * 16 + rr;
        ushort4 o;
        o.x = tl[crow][cc + 0]; o.y = tl[crow][cc + 1];
        o.z = tl[crow][cc + 2]; o.w = tl[crow][cc + 3];
        *(ushort4*)(dst + (size_t)(c0 + crow) * R + r0 + cc) = o;
    }
}

// ---------------- SpMM: 2 rows/wave, 32 lanes x 16B, MASKED unroll-8 ----------------
__global__ void spmm_bf16(const int* __restrict__ rowptr, const int2* __restrict__ cw,
                          const u16* __restrict__ xb, u16* __restrict__ outb, int n) {
    int tid = threadIdx.x;
    int lane = tid & 63;
    int row = blockIdx.x * 8 + ((tid >> 6) << 1) + (lane >> 5);
    if (row >= n) return;
    int l32 = lane & 31;
    int p0 = rowptr[row], p1 = rowptr[row + 1];
    float a[8];
    #pragma unroll
    for (int j = 0; j < 8; ++j) a[j] = 0.f;

    for (int p = p0; p < p1; p += 8) {
        int2 cwv[8]; uint4 v[8];
        #pragma unroll
        for (int u = 0; u < 8; ++u) {
            int q = p + u;
            bool ok = q < p1;
            cwv[u] = cw[ok ? q : p0];
            if (!ok) cwv[u].y = 0;          // weight := 0.0f
        }
        #pragma unroll
        for (int u = 0; u < 8; ++u)
            v[u] = *(const uint4*)(xb + (size_t)cwv[u].x * FD + l32 * 8);
        #pragma unroll
        for (int u = 0; u < 8; ++u) {
            float wt = __int_as_float(cwv[u].y);
            a[0] += wt * bfl(v[u].x); a[1] += wt * bfh(v[u].x);
            a[2] += wt * bfl(v[u].y); a[3] += wt * bfh(v[u].y);
            a[4] += wt * bfl(v[u].z); a[5] += wt * bfh(v[u].z);
            a[6] += wt * bfl(v[u].w); a[7] += wt * bfh(v[u].w);
        }
    }
    uint4 o;
    o.x = (u32)f2bf(a[0]) | ((u32)f2bf(a[1]) << 16);
    o.y = (u32)f2bf(a[2]) | ((u32)f2bf(a[3]) << 16);
    o.z = (u32)f2bf(a[4]) | ((u32)f2bf(a[5]) << 16);
    o.w = (u32)f2bf(a[6]) | ((u32)f2bf(a[7]) << 16);
    *(uint4*)(outb + (size_t)row * FD + l32 * 8) = o;
}

// ---------------- fused_gemm v7 ----------------
// 64 rows/block, 4 waves. LDS (64 KB):
//   RA [0,32K):  A tile [64 r][256 k] (rows 512B, granule^(r&7)); after stage B
//                aliased by WcT [64 c][256 k] (same swizzle form).
//   RW [32K,64K): per-wave private W dbuf (wave w: RW+w*8192, 2 x 4KB,
//                [64 j'][64B] rows, slot^(j&3)); after stage B aliased by
//                Tl [64 r][256 j] (rows 512B, granule^(r&7)).
// Stage B: NO barriers -- W staged per-wave, synced by that wave's own vmcnt.
__launch_bounds__(256, 2)
__global__ void fused_gemm(const u16* __restrict__ xb, const u16* __restrict__ agg1b,
                           const u16* __restrict__ agg2b, const u16* __restrict__ WkT,
                           const float* __restrict__ b0, const float* __restrict__ b1,
                           const float* __restrict__ b2, const u16* __restrict__ WcT,
                           const float* __restrict__ bc, float* __restrict__ out, int n) {
    __shared__ __align__(16) char lds[65536];
    char* RA = lds;
    char* RW = lds + 32768;

    const int tid = threadIdx.x;
    const int w = tid >> 6, l = tid & 63;
    const int l4 = l >> 4, lm = l & 15;
    const int row0 = blockIdx.x * 64;
    const int rr = w * 16 + lm;        // stage-C row owned by this lane
    char* myW = RW + w * 8192;         // wave-private 2 x 4KB W buffers

    // A tile -> RA (linear dest, pre-swizzled source; verified v2/v5 pattern)
    auto stageA = [&](const u16* inb) {
        #pragma unroll
        for (int i = 0; i < 8; ++i) {
            int L = tid * 16 + i * 4096;
            int r = L >> 9, g = (L >> 4) & 31;
            int gr = row0 + r; if (gr > n - 1) gr = n - 1;
            gll16(inb + (size_t)gr * FD + (g ^ (r & 7)) * 8, RA + L);
        }
    };
    // wave-private W quarter, slice kt -> myW[pb] (4 gll16/lane)
    auto stageW = [&](const u16* WT, int kt, int pb) {
        #pragma unroll
        for (int i = 0; i < 4; ++i) {
            int L = l * 16 + i * 1024;
            int jq = L >> 6, s = (L >> 4) & 3;
            int j = w * 64 + jq;
            gll16(WT + (size_t)j * FD + kt * 32 + (s ^ (j & 3)) * 8,
                  myW + pb * 4096 + L);
        }
    };
    // WcT(seg) whole 32KB -> RA (verified v2 pattern)
    auto stageWc = [&](int seg) {
        #pragma unroll
        for (int i = 0; i < 8; ++i) {
            int L = tid * 16 + i * 4096;
            int c = L >> 9, g = (L >> 4) & 31;
            gll16(WcT + (size_t)c * 768 + seg * 256 + (g ^ (c & 7)) * 8, RA + L);
        }
    };

    f32x4 oacc[4];
    #pragma unroll
    for (int am = 0; am < 4; ++am) oacc[am] = (f32x4)(0.f);

    stageA(xb);
    stageW(WkT, 0, 0);
    WVM0();
    BAR();                             // A(0) + W0 resident

    for (int seg = 0; seg < 3; ++seg) {
        const u16* WT = WkT + (size_t)seg * 65536;
        const float* bk = (seg == 0) ? b0 : (seg == 1) ? b1 : b2;

        // ---- stage B: ZERO barriers; per-wave private W pipeline ----
        f32x4 acc[4][4];
        #pragma unroll
        for (int jm = 0; jm < 4; ++jm)
            #pragma unroll
            for (int rn = 0; rn < 4; ++rn) acc[jm][rn] = (f32x4)(0.f);

        #pragma unroll
        for (int kt = 0; kt < 8; ++kt) {
            if (kt < 7) stageW(WT, kt + 1, (kt + 1) & 1);  // +4 outstanding
            if (kt == 7)      { WVM0(); }                   // last slice resident
            else if (kt > 0)  { WVM4(); }                   // W(kt) resident; W(kt+1) flying
            char* curW = myW + (kt & 1) * 4096;

            frag_ab af[4], bf_[4];
            #pragma unroll
            for (int jm = 0; jm < 4; ++jm) {
                int jq = jm * 16 + lm;
                int j  = w * 64 + jq;
                af[jm] = *(const frag_ab*)(curW + jq * 64 + ((l4 ^ (j & 3)) << 4));
            }
            #pragma unroll
            for (int rn = 0; rn < 4; ++rn) {
                int r = rn * 16 + lm;
                bf_[rn] = *(const frag_ab*)(RA + r * 512 + (((kt * 4 + l4) ^ (r & 7)) << 4));
            }
            #pragma unroll
            for (int jm = 0; jm < 4; ++jm)
                #pragma unroll
                for (int rn = 0; rn < 4; ++rn)
                    acc[jm][rn] = __builtin_amdgcn_mfma_f32_16x16x32_bf16(af[jm], bf_[rn], acc[jm][rn], 0, 0, 0);
        }
        WLG0();                        // my frag reads retired
        BAR();                         // all waves done stage B -> RA/RW reusable

        stageWc(seg);                  // WcT(seg) -> RA (A dead)

        // ---- pack: relu(acc + bk) -> Tl (= RW region; W buffers dead) ----
        char* Tl = RW;
        #pragma unroll
        for (int jm = 0; jm < 4; ++jm) {
            int j0 = w * 64 + jm * 16 + l4 * 4;
            float4 bb = *(const float4*)(bk + j0);
            #pragma unroll
            for (int rn = 0; rn < 4; ++rn) {
                int r = rn * 16 + lm;
                f32x4 v = acc[jm][rn];
                ushort4 p;
                p.x = f2bf(fmaxf(v[0] + bb.x, 0.f));
                p.y = f2bf(fmaxf(v[1] + bb.y, 0.f));
                p.z = f2bf(fmaxf(v[2] + bb.z, 0.f));
                p.w = f2bf(fmaxf(v[3] + bb.w, 0.f));
                *(ushort4*)(Tl + r * 512 + (((j0 >> 3) ^ (r & 7)) << 4) + (j0 & 7) * 2) = p;
            }
        }
        WVM0();                        // WcT resident
        WLG0();                        // pack writes committed
        BAR();                         // Tl + WcT ready for everyone

        // ---- stage C: out += Tl @ WcT ; zero internal barriers ----
        #pragma unroll
        for (int ks = 0; ks < 8; ++ks) {
            frag_ab tb = *(const frag_ab*)(Tl + rr * 512 + (((ks * 4 + l4) ^ (rr & 7)) << 4));
            #pragma unroll
            for (int am = 0; am < 4; ++am) {
                int c = am * 16 + lm;
                frag_ab afr = *(const frag_ab*)(RA + c * 512 + (((ks * 4 + l4) ^ (c & 7)) << 4));
                oacc[am] = __builtin_amdgcn_mfma_f32_16x16x32_bf16(afr, tb, oacc[am], 0, 0, 0);
            }
        }
        WLG0();                        // Tl + WcT reads retired
        BAR();                         // RA/RW free for next seg staging

        if (seg < 2) {
            stageA((seg == 0) ? agg1b : agg2b);
            stageW(WkT + (size_t)(seg + 1) * 65536, 0, 0);
            WVM0();
            BAR();                     // next A + W0 resident
        }
    }

    int gr = row0 + rr;
    if (gr < n) {
        #pragma unroll
        for (int am = 0; am < 4; ++am) {
            float4 bb = *(const float4*)(bc + am * 16 + l4 * 4);
            float4 o;
            o.x = oacc[am][0] + bb.x;
            o.y = oacc[am][1] + bb.y;
            o.z = oacc[am][2] + bb.z;
            o.w = oacc[am][3] + bb.w;
            *(float4*)(out + (size_t)gr * CO + am * 16 + l4 * 4) = o;
        }
    }
}

extern "C" void kernel_launch(void* const* d_in, const int* in_sizes, int n_in,
                              void* d_out, int out_size, void* d_ws, size_t ws_size,
                              hipStream_t stream) {
    const float* x  = (const float*)d_in[0];
    const int*   ei = (const int*)d_in[1];
    const float* W0 = (const float*)d_in[3];
    const float* b0 = (const float*)d_in[4];
    const float* W1 = (const float*)d_in[5];
    const float* b1 = (const float*)d_in[6];
    const float* W2 = (const float*)d_in[7];
    const float* b2 = (const float*)d_in[8];
    const float* Wc = (const float*)d_in[9];
    const float* bc = (const float*)d_in[10];
    float* out = (float*)d_out;

    const int n  = in_sizes[0] / FD;   // 50000
    const int e  = in_sizes[1] / 2;    // 400000
    const int ep = e + n;
    const int nb = (n + SB - 1) / SB;

    char* ws = (char*)d_ws;
    size_t o = 0;
    auto take = [&](size_t nbytes) -> char* {
        char* p = ws + o;
        o += (nbytes + 255) & ~(size_t)255;
        return p;
    };
    int*   deg    = (int*)  take((size_t)n * 4);
    int*   fill   = (int*)  take((size_t)n * 4);
    float* dis    = (float*)take((size_t)n * 4);
    int*   rowptr = (int*)  take((size_t)(n + 1) * 4);
    int*   bsum   = (int*)  take((size_t)(nb + 1) * 4);
    int*   bscan  = (int*)  take((size_t)(nb + 1) * 4);
    int2*  cw     = (int2*) take((size_t)ep * 8);
    u16*   xb     = (u16*)  take((size_t)n * FD * 2);
    u16*   agg1b  = (u16*)  take((size_t)n * FD * 2);
    u16*   agg2b  = (u16*)  take((size_t)n * FD * 2);
    u16*   WkT    = (u16*)  take((size_t)3 * FD * FD * 2);
    u16*   WcT    = (u16*)  take((size_t)CO * 3 * FD * 2);
    (void)ws_size; (void)n_in; (void)out_size;

    const int n4 = (n + 3) / 4;
    zerok       <<<(n4 + 255) / 256, 256, 0, stream>>>((int4*)deg, (int4*)fill, n4);
    count_kernel<<<(e + 255) / 256, 256, 0, stream>>>(ei, deg, e);
    scan1       <<<nb, SB, 0, stream>>>(deg, rowptr, bsum, dis, n);
    scan2       <<<1, 128, 0, stream>>>(bsum, bscan, nb);
    scan3       <<<(n + 256) / 256, 256, 0, stream>>>(rowptr, bscan, n, nb);
    fill_kernel <<<(ep + 255) / 256, 256, 0, stream>>>(ei, dis, rowptr, fill, cw, e, n);

    const int total4 = n * FD / 4;
    const int cb = (total4 + 255) / 256;
    prep_kernel<<<cb + 60, 256, 0, stream>>>(x, xb, total4, cb, W0, W1, W2, Wc, WkT, WcT);

    spmm_bf16<<<(n + 7) / 8, 256, 0, stream>>>(rowptr, cw, xb, agg1b, n);
    spmm_bf16<<<(n + 7) / 8, 256, 0, stream>>>(rowptr, cw, agg1b, agg2b, n);

    fused_gemm<<<(n + 63) / 64, 256, 0, stream>>>(xb, agg1b, agg2b, WkT,
                                                  b0, b1, b2, WcT, bc, out, n);
}

// Round 22
// 187.038 us; speedup vs baseline: 1.0409x; 1.0409x over previous
//
#include <hip/hip_runtime.h>

// H2GCN final: prep(conv+wtrans+zero) -> count -> scan1 -> scan23 -> fill ->
// bf16 SpMM x2 (masked unroll-8, at gather-BW roofline) -> fused_gemm v1
// (verified best structure). 8 launches (was 10).

#define FD 256    // D == H == 256
#define CO 64     // out channels
#define SB 512    // scan block

using frag_ab = __attribute__((ext_vector_type(8))) short;  // 8 bf16
using f32x4   = __attribute__((ext_vector_type(4))) float;
typedef unsigned short u16;
typedef unsigned int   u32;

__device__ __forceinline__ u16 f2bf(float f) {
    u32 u = __builtin_bit_cast(u32, f);
    return (u16)((u + 0x7FFFu + ((u >> 16) & 1u)) >> 16);
}
__device__ __forceinline__ float bfl(u32 packed) {          // low bf16
    return __builtin_bit_cast(float, packed << 16);
}
__device__ __forceinline__ float bfh(u32 packed) {          // high bf16
    return __builtin_bit_cast(float, packed & 0xFFFF0000u);
}

__device__ __forceinline__ void gll16(const void* g, void* l) {
    __builtin_amdgcn_global_load_lds(
        (const __attribute__((address_space(1))) u32*)g,
        (__attribute__((address_space(3))) u32*)l, 16, 0, 0);
}

#define BAR()  __builtin_amdgcn_s_barrier()
#define WLG0() asm volatile("s_waitcnt lgkmcnt(0)" ::: "memory")
#define WVM0() asm volatile("s_waitcnt vmcnt(0)" ::: "memory")
#define WVM2() asm volatile("s_waitcnt vmcnt(2)" ::: "memory")

// ---------------- prep: x->bf16 (blocks<cb) + W transpose (cb..cb+60) + zero (>=cb+60) ----------------
__global__ void prep_kernel(const float* __restrict__ x, u16* __restrict__ xb, int total4, int cb,
                            const float* __restrict__ W0, const float* __restrict__ W1,
                            const float* __restrict__ W2, const float* __restrict__ Wc,
                            u16* __restrict__ WkT, u16* __restrict__ WcT,
                            int4* __restrict__ deg4, int4* __restrict__ fill4, int n4) {
    __shared__ u16 tl[64][65];
    if (blockIdx.x < cb) {             // x -> bf16
        int i = blockIdx.x * blockDim.x + threadIdx.x;
        if (i < total4) {
            float4 v = ((const float4*)x)[i];
            ushort4 o;
            o.x = f2bf(v.x); o.y = f2bf(v.y); o.z = f2bf(v.z); o.w = f2bf(v.w);
            ((ushort4*)xb)[i] = o;
        }
        return;
    }
    if (blockIdx.x >= cb + 60) {       // zero deg/fill
        int i = (blockIdx.x - cb - 60) * blockDim.x + threadIdx.x;
        int4 z = make_int4(0, 0, 0, 0);
        if (i < n4) { deg4[i] = z; fill4[i] = z; }
        return;
    }
    int b = blockIdx.x - cb;           // 0..59: weight transpose
    const float* src; u16* dst; int R, C, r0, c0;
    if (b < 48) {
        int k = b >> 4, t = b & 15;
        src = (k == 0) ? W0 : (k == 1) ? W1 : W2;
        dst = WkT + k * 65536;
        R = 256; C = 256; r0 = (t >> 2) * 64; c0 = (t & 3) * 64;
    } else {
        int t = b - 48;
        src = Wc; dst = WcT;
        R = 768; C = 64; r0 = t * 64; c0 = 0;
    }
    int tid = threadIdx.x;
    int rr = tid >> 4, cc = (tid & 15) * 4;
    #pragma unroll
    for (int it = 0; it < 4; ++it) {
        int r = it * 16 + rr;
        float4 v = *(const float4*)(src + (size_t)(r0 + r) * C + c0 + cc);
        tl[cc + 0][r] = f2bf(v.x); tl[cc + 1][r] = f2bf(v.y);
        tl[cc + 2][r] = f2bf(v.z); tl[cc + 3][r] = f2bf(v.w);
    }
    __syncthreads();
    #pragma unroll
    for (int it = 0; it < 4; ++it) {
        int crow = it * 16 + rr;
        ushort4 o;
        o.x = tl[crow][cc + 0]; o.y = tl[crow][cc + 1];
        o.z = tl[crow][cc + 2]; o.w = tl[crow][cc + 3];
        *(ushort4*)(dst + (size_t)(c0 + crow) * R + r0 + cc) = o;
    }
}

// ---------------- CSR build ----------------
__global__ void count_kernel(const int* __restrict__ ei0, int* deg, int e) {
    int i = blockIdx.x * blockDim.x + threadIdx.x;
    if (i < e) atomicAdd(&deg[ei0[i]], 1);
}
// deg holds RAW edge counts; +1 self-loop added here
__global__ void scan1(const int* __restrict__ deg, int* __restrict__ rowptr,
                      int* __restrict__ bsum, float* __restrict__ dis, int n) {
    __shared__ int sh[SB];
    int tid = threadIdx.x;
    int i = blockIdx.x * SB + tid;
    int v = (i < n) ? deg[i] + 1 : 0;
    if (i < n) dis[i] = rsqrtf((float)v);
    sh[tid] = v;
    __syncthreads();
    for (int off = 1; off < SB; off <<= 1) {
        int add = (tid >= off) ? sh[tid - off] : 0;
        __syncthreads();
        sh[tid] += add;
        __syncthreads();
    }
    if (i < n) rowptr[i] = sh[tid] - v;
    if (tid == SB - 1) bsum[blockIdx.x] = sh[tid];
}
// merged scan2+scan3: every block redundantly scans bsum[0..nb) then applies
__global__ void scan23(const int* __restrict__ bsum, int* __restrict__ rowptr, int n, int nb) {
    __shared__ int inc[128];
    __shared__ int exc[129];
    int tid = threadIdx.x;
    if (tid < 128) inc[tid] = (tid < nb) ? bsum[tid] : 0;
    __syncthreads();
    for (int off = 1; off < 128; off <<= 1) {
        int add = 0;
        if (tid < 128 && tid >= off) add = inc[tid - off];
        __syncthreads();
        if (tid < 128) inc[tid] += add;
        __syncthreads();
    }
    if (tid < 128) exc[tid] = inc[tid] - ((tid < nb) ? bsum[tid] : 0);
    if (tid == 0) exc[nb] = inc[nb - 1];          // total (same value any writer)
    __syncthreads();
    int i = blockIdx.x * 256 + tid;
    if (i < n) rowptr[i] += exc[i / SB];
    if (i == n) rowptr[n] = exc[nb];
}
__global__ void fill_kernel(const int* __restrict__ ei, const float* __restrict__ dis,
                            const int* __restrict__ rowptr, int* fill,
                            int2* __restrict__ cw, int e, int n) {
    int i = blockIdx.x * blockDim.x + threadIdx.x;
    if (i >= e + n) return;
    int r, c;
    if (i < e) { r = ei[i]; c = ei[e + i]; }
    else       { r = i - e; c = r; }
    float w = dis[r] * dis[c];
    int pos = rowptr[r] + atomicAdd(&fill[r], 1);
    int2 p; p.x = c; p.y = __float_as_int(w);
    cw[pos] = p;
}

// ---------------- SpMM: 2 rows/wave, 32 lanes x 16B, MASKED unroll-8 ----------------
__global__ void spmm_bf16(const int* __restrict__ rowptr, const int2* __restrict__ cw,
                          const u16* __restrict__ xb, u16* __restrict__ outb, int n) {
    int tid = threadIdx.x;
    int lane = tid & 63;
    int row = blockIdx.x * 8 + ((tid >> 6) << 1) + (lane >> 5);
    if (row >= n) return;
    int l32 = lane & 31;
    int p0 = rowptr[row], p1 = rowptr[row + 1];
    float a[8];
    #pragma unroll
    for (int j = 0; j < 8; ++j) a[j] = 0.f;

    for (int p = p0; p < p1; p += 8) {
        int2 cwv[8]; uint4 v[8];
        #pragma unroll
        for (int u = 0; u < 8; ++u) {
            int q = p + u;
            bool ok = q < p1;
            cwv[u] = cw[ok ? q : p0];
            if (!ok) cwv[u].y = 0;          // weight := 0.0f
        }
        #pragma unroll
        for (int u = 0; u < 8; ++u)
            v[u] = *(const uint4*)(xb + (size_t)cwv[u].x * FD + l32 * 8);
        #pragma unroll
        for (int u = 0; u < 8; ++u) {
            float wt = __int_as_float(cwv[u].y);
            a[0] += wt * bfl(v[u].x); a[1] += wt * bfh(v[u].x);
            a[2] += wt * bfl(v[u].y); a[3] += wt * bfh(v[u].y);
            a[4] += wt * bfl(v[u].z); a[5] += wt * bfh(v[u].z);
            a[6] += wt * bfl(v[u].w); a[7] += wt * bfh(v[u].w);
        }
    }
    uint4 o;
    o.x = (u32)f2bf(a[0]) | ((u32)f2bf(a[1]) << 16);
    o.y = (u32)f2bf(a[2]) | ((u32)f2bf(a[3]) << 16);
    o.z = (u32)f2bf(a[4]) | ((u32)f2bf(a[5]) << 16);
    o.w = (u32)f2bf(a[6]) | ((u32)f2bf(a[7]) << 16);
    *(uint4*)(outb + (size_t)row * FD + l32 * 8) = o;
}

// ---------------- fused_gemm (round-12/16/20 v1, verified best) ----------------
// 64 rows/block. LDS map (72 KB):
//   ppA  [0,8K):    2 x 4KB  in slices (64 r x 32 k), rows 64B, slot^(r&3)
//   ppW  [8K,40K):  2 x 16KB Wk slices (256 j x 32 k), rows 64B, slot^(j&3)
//   Tl   [40K,72K): T tile (64 r x 256 j bf16), rows 512B, granule^(r&7)
//   wcpp aliases [8K,16K)+[16K,24K): 2 x 8KB WcT slices (64 c x 64 k), rows 128B, slot^(c&7)
__launch_bounds__(256, 2)
__global__ void fused_gemm(const u16* __restrict__ xb, const u16* __restrict__ agg1b,
                           const u16* __restrict__ agg2b, const u16* __restrict__ WkT,
                           const float* __restrict__ b0, const float* __restrict__ b1,
                           const float* __restrict__ b2, const u16* __restrict__ WcT,
                           const float* __restrict__ bc, float* __restrict__ out, int n) {
    __shared__ __align__(16) char lds[73728];
    char* Tl = lds + 40960;

    const int tid = threadIdx.x;
    const int w = tid >> 6, l = tid & 63;
    const int l4 = l >> 4, lm = l & 15;
    const int row0 = blockIdx.x * 64;
    const int rr = w * 16 + lm;        // stage-C row owned by this lane

    f32x4 oacc[4];
    #pragma unroll
    for (int am = 0; am < 4; ++am) oacc[am] = (f32x4)(0.f);

    for (int seg = 0; seg < 3; ++seg) {
        const u16* inb = (seg == 0) ? xb : (seg == 1) ? agg1b : agg2b;
        const u16* WT  = WkT + (size_t)seg * 65536;
        const float* bk = (seg == 0) ? b0 : (seg == 1) ? b1 : b2;

        // stage in(4KB)+Wk(16KB) K-slice kt into ping-pong buffer pb
        auto stageB = [&](int kt, int pb) {
            {
                int L = tid * 16;
                int r = L >> 6, s = (L >> 4) & 3;
                int gr = row0 + r; if (gr > n - 1) gr = n - 1;
                gll16(inb + (size_t)gr * FD + kt * 32 + (s ^ (r & 3)) * 8,
                      lds + pb * 4096 + L);
            }
            #pragma unroll
            for (int i = 0; i < 4; ++i) {
                int L = tid * 16 + i * 4096;
                int j = L >> 6, s = (L >> 4) & 3;
                gll16(WT + (size_t)j * FD + kt * 32 + (s ^ (j & 3)) * 8,
                      lds + 8192 + pb * 16384 + L);
            }
        };

        // ---- stage B: T_tile[64][256] = in @ Wk (wave w owns j in [w*64, w*64+64)) ----
        f32x4 acc[4][4];
        #pragma unroll
        for (int jm = 0; jm < 4; ++jm)
            #pragma unroll
            for (int rn = 0; rn < 4; ++rn) acc[jm][rn] = (f32x4)(0.f);

        stageB(0, 0);
        WVM0();
        BAR();

        #pragma unroll
        for (int kt = 0; kt < 8; ++kt) {
            char* curA = lds + (kt & 1) * 4096;
            char* curW = lds + 8192 + (kt & 1) * 16384;
            if (kt < 7) stageB(kt + 1, (kt + 1) & 1);   // rides under compute

            frag_ab af[4], bf_[4];
            #pragma unroll
            for (int jm = 0; jm < 4; ++jm) {
                int j = w * 64 + jm * 16 + lm;
                af[jm] = *(const frag_ab*)(curW + j * 64 + ((l4 ^ (j & 3)) << 4));
            }
            #pragma unroll
            for (int rn = 0; rn < 4; ++rn) {
                int r = rn * 16 + lm;
                bf_[rn] = *(const frag_ab*)(curA + r * 64 + ((l4 ^ (r & 3)) << 4));
            }
            #pragma unroll
            for (int jm = 0; jm < 4; ++jm)
                #pragma unroll
                for (int rn = 0; rn < 4; ++rn)
                    acc[jm][rn] = __builtin_amdgcn_mfma_f32_16x16x32_bf16(af[jm], bf_[rn], acc[jm][rn], 0, 0, 0);

            if (kt < 7) WVM0();        // next buffer resident (latency hidden)
            WLG0();                    // my LDS frag reads retired
            BAR();                     // all waves done with cur -> restage ok
        }

        // stage WcT c-rows x 64k slice kt2 into wc ping-pong pb (aliases ppW region)
        auto stageC = [&](int kt2, int pb) {
            #pragma unroll
            for (int i = 0; i < 2; ++i) {
                int L = tid * 16 + i * 4096;
                int c = L >> 7, s = (L >> 4) & 7;
                gll16(WcT + (size_t)c * 768 + seg * 256 + kt2 * 64 + (s ^ (c & 7)) * 8,
                      lds + 8192 + pb * 8192 + L);
            }
        };
        stageC(0, 0);                  // issue early: rides under T-write VALU

        // ---- bias + relu + pack T_tile into Tl (swizzled) ----
        #pragma unroll
        for (int jm = 0; jm < 4; ++jm) {
            int j0 = w * 64 + jm * 16 + l4 * 4;
            float4 bb = *(const float4*)(bk + j0);
            #pragma unroll
            for (int rn = 0; rn < 4; ++rn) {
                int r = rn * 16 + lm;
                f32x4 v = acc[jm][rn];
                ushort4 p;
                p.x = f2bf(fmaxf(v[0] + bb.x, 0.f));
                p.y = f2bf(fmaxf(v[1] + bb.y, 0.f));
                p.z = f2bf(fmaxf(v[2] + bb.z, 0.f));
                p.w = f2bf(fmaxf(v[3] + bb.w, 0.f));
                *(ushort4*)(Tl + r * 512 + (((j0 >> 3) ^ (r & 7)) << 4) + (j0 & 7) * 2) = p;
            }
        }
        WLG0();                        // T writes committed
        BAR();

        // ---- stage C: out += T_tile @ WcT_seg ----
        #pragma unroll
        for (int kt2 = 0; kt2 < 4; ++kt2) {
            char* cw_ = lds + 8192 + (kt2 & 1) * 8192;
            if (kt2 < 3) {
                stageC(kt2 + 1, (kt2 + 1) & 1);
                WVM2();                // cur slice's 2 loads landed; next 2 in flight
            } else {
                WVM0();
            }
            BAR();
            #pragma unroll
            for (int kk2 = 0; kk2 < 2; ++kk2) {
                int g = kt2 * 8 + kk2 * 4 + l4;
                frag_ab bfr = *(const frag_ab*)(Tl + rr * 512 + ((g ^ (rr & 7)) << 4));
                #pragma unroll
                for (int am = 0; am < 4; ++am) {
                    int c = am * 16 + lm;
                    frag_ab afr = *(const frag_ab*)(cw_ + c * 128 + (((kk2 * 4 + l4) ^ (c & 7)) << 4));
                    oacc[am] = __builtin_amdgcn_mfma_f32_16x16x32_bf16(afr, bfr, oacc[am], 0, 0, 0);
                }
            }
            WLG0();                    // my LDS frag reads complete
            BAR();                     // all waves done with cur -> restage ok
        }
    }

    int gr = row0 + rr;
    if (gr < n) {
        #pragma unroll
        for (int am = 0; am < 4; ++am) {
            float4 bb = *(const float4*)(bc + am * 16 + l4 * 4);
            float4 o;
            o.x = oacc[am][0] + bb.x;
            o.y = oacc[am][1] + bb.y;
            o.z = oacc[am][2] + bb.z;
            o.w = oacc[am][3] + bb.w;
            *(float4*)(out + (size_t)gr * CO + am * 16 + l4 * 4) = o;
        }
    }
}

extern "C" void kernel_launch(void* const* d_in, const int* in_sizes, int n_in,
                              void* d_out, int out_size, void* d_ws, size_t ws_size,
                              hipStream_t stream) {
    const float* x  = (const float*)d_in[0];
    const int*   ei = (const int*)d_in[1];
    const float* W0 = (const float*)d_in[3];
    const float* b0 = (const float*)d_in[4];
    const float* W1 = (const float*)d_in[5];
    const float* b1 = (const float*)d_in[6];
    const float* W2 = (const float*)d_in[7];
    const float* b2 = (const float*)d_in[8];
    const float* Wc = (const float*)d_in[9];
    const float* bc = (const float*)d_in[10];
    float* out = (float*)d_out;

    const int n  = in_sizes[0] / FD;   // 50000
    const int e  = in_sizes[1] / 2;    // 400000
    const int ep = e + n;
    const int nb = (n + SB - 1) / SB;

    char* ws = (char*)d_ws;
    size_t o = 0;
    auto take = [&](size_t nbytes) -> char* {
        char* p = ws + o;
        o += (nbytes + 255) & ~(size_t)255;
        return p;
    };
    int*   deg    = (int*)  take((size_t)n * 4);
    int*   fill   = (int*)  take((size_t)n * 4);
    float* dis    = (float*)take((size_t)n * 4);
    int*   rowptr = (int*)  take((size_t)(n + 1) * 4);
    int*   bsum   = (int*)  take((size_t)(nb + 1) * 4);
    int2*  cw     = (int2*) take((size_t)ep * 8);
    u16*   xb     = (u16*)  take((size_t)n * FD * 2);
    u16*   agg1b  = (u16*)  take((size_t)n * FD * 2);
    u16*   agg2b  = (u16*)  take((size_t)n * FD * 2);
    u16*   WkT    = (u16*)  take((size_t)3 * FD * FD * 2);
    u16*   WcT    = (u16*)  take((size_t)CO * 3 * FD * 2);
    (void)ws_size; (void)n_in; (void)out_size;

    const int total4 = n * FD / 4;
    const int cb = (total4 + 255) / 256;
    const int n4 = (n + 3) / 4;
    const int zb = (n4 + 255) / 256;

    prep_kernel <<<cb + 60 + zb, 256, 0, stream>>>(x, xb, total4, cb, W0, W1, W2, Wc,
                                                   WkT, WcT, (int4*)deg, (int4*)fill, n4);
    count_kernel<<<(e + 255) / 256, 256, 0, stream>>>(ei, deg, e);
    scan1       <<<nb, SB, 0, stream>>>(deg, rowptr, bsum, dis, n);
    scan23      <<<(n + 256) / 256, 256, 0, stream>>>(bsum, rowptr, n, nb);
    fill_kernel <<<(ep + 255) / 256, 256, 0, stream>>>(ei, dis, rowptr, fill, cw, e, n);

    spmm_bf16<<<(n + 7) / 8, 256, 0, stream>>>(rowptr, cw, xb, agg1b, n);
    spmm_bf16<<<(n + 7) / 8, 256, 0, stream>>>(rowptr, cw, agg1b, agg2b, n);

    fused_gemm<<<(n + 63) / 64, 256, 0, stream>>>(xb, agg1b, agg2b, WkT,
                                                  b0, b1, b2, WcT, bc, out, n);
}